// Round 1
// baseline (547.026 us; speedup 1.0000x reference)
//
#include <hip/hip_runtime.h>
#include <math.h>

// Problem constants (reference: B,T,D = 128,2048,256; LAMDA=0.5)
#define BB 128
#define TT 2048
#define DD 256
#define SPLIT 8
#define ROWS_PER_BLOCK (TT / SPLIT)           // 256
#define WAVES 4
#define ROWS_PER_WAVE (ROWS_PER_BLOCK / WAVES) // 64

// Workspace layout (in floats)
#define WS_MIDS 0                               // B*D
#define WS_P1ACC (WS_MIDS + BB * DD)            // B*SPLIT*D
#define WS_P1SUM (WS_P1ACC + BB * SPLIT * DD)   // B*SPLIT
#define WS_P2ACC_SS (WS_P1SUM + BB * SPLIT)     // B*SPLIT*D
#define WS_P2ACC_SA (WS_P2ACC_SS + BB * SPLIT * DD) // B*SPLIT*D
#define WS_P2SUM_SS (WS_P2ACC_SA + BB * SPLIT * DD) // B*SPLIT
#define WS_P2SUM_SA (WS_P2SUM_SS + BB * SPLIT)      // B*SPLIT
// total = 822272 floats = ~3.3 MB

__device__ __forceinline__ float wave_reduce_add(float v) {
    #pragma unroll
    for (int off = 32; off > 0; off >>= 1)
        v += __shfl_xor(v, off, 64);
    return v;
}

__device__ __forceinline__ float dot4(const float4& a, const float4& b) {
    return a.x * b.x + a.y * b.y + a.z * b.z + a.w * b.w;
}

// Overflow-safe tanh: tanh(x) = sign(x) * (1 - e^{-2|x|}) / (1 + e^{-2|x|})
__device__ __forceinline__ float tanh_fast(float x) {
    float ax = fabsf(x);
    float t = __expf(-2.0f * ax);     // in (0,1], never overflows
    float th = (1.0f - t) / (1.0f + t);
    return copysignf(th, x);
}

// K0: mids[b,i] = sum_j aspect[b,j] * W_mul[i,j]   (aspect @ W_mul.T)
__global__ __launch_bounds__(DD) void mids_kernel(
    const float* __restrict__ aspect, const float* __restrict__ W,
    float* __restrict__ ws)
{
    const int b = blockIdx.x;
    const int i = threadIdx.x;
    __shared__ float a[DD];
    a[i] = aspect[b * DD + i];
    __syncthreads();
    const float4* wrow = (const float4*)(W + (size_t)i * DD);
    float acc = 0.f;
    #pragma unroll 8
    for (int j4 = 0; j4 < DD / 4; ++j4) {
        float4 w4 = wrow[j4];
        acc += a[4 * j4 + 0] * w4.x + a[4 * j4 + 1] * w4.y +
               a[4 * j4 + 2] * w4.z + a[4 * j4 + 3] * w4.w;
    }
    ws[WS_MIDS + b * DD + i] = acc;
}

// K_main: grid (SPLIT, B, 2).  z=0: aspect (multiplicative) pass over
// aspect_memory; z=1: sentiment (two additive heads) pass over
// sentiment_memory.  One wave per row: lane l holds columns 4l..4l+3.
// No max-subtraction needed (scores bounded; softmax shift-invariant),
// so partials are linear sums.
__global__ __launch_bounds__(256) void pass_kernel(
    const float* __restrict__ smem_g, const float* __restrict__ amem_g,
    const float* __restrict__ mask, const float* __restrict__ w_ss,
    const float* __restrict__ w_sa, const float* __restrict__ b_mul,
    float* __restrict__ ws)
{
    const int s = blockIdx.x;
    const int b = blockIdx.y;
    const int tid = threadIdx.x;
    const int wave = tid >> 6;
    const int lane = tid & 63;
    const int t0 = s * ROWS_PER_BLOCK + wave * ROWS_PER_WAVE;

    __shared__ __align__(16) float lds_acc[2 * WAVES * DD]; // 8 KB
    __shared__ float lds_sum[2 * WAVES];

    if (blockIdx.z == 0) {
        // ---- aspect pass: score = tanh(mem . mids + b_mul) ----
        const float4 m4 = *(const float4*)(ws + WS_MIDS + b * DD + lane * 4);
        const float bm = b_mul[0];
        const float* base = amem_g + ((size_t)b * TT + t0) * DD + lane * 4;
        float4 acc = make_float4(0.f, 0.f, 0.f, 0.f);
        float lsum = 0.f;
        for (int r = 0; r < ROWS_PER_WAVE; r += 2) {
            float4 v0 = *(const float4*)(base + (size_t)r * DD);
            float4 v1 = *(const float4*)(base + (size_t)(r + 1) * DD);
            float d0 = wave_reduce_add(dot4(v0, m4));
            float d1 = wave_reduce_add(dot4(v1, m4));
            float e0 = __expf(tanh_fast(d0 + bm));
            float e1 = __expf(tanh_fast(d1 + bm));
            lsum += e0 + e1;
            acc.x += e0 * v0.x + e1 * v1.x;
            acc.y += e0 * v0.y + e1 * v1.y;
            acc.z += e0 * v0.z + e1 * v1.z;
            acc.w += e0 * v0.w + e1 * v1.w;
        }
        ((float4*)(lds_acc + wave * DD))[lane] = acc;
        if (lane == 0) lds_sum[wave] = lsum;
        __syncthreads();
        float tot = lds_acc[0 * DD + tid] + lds_acc[1 * DD + tid] +
                    lds_acc[2 * DD + tid] + lds_acc[3 * DD + tid];
        ws[WS_P1ACC + (size_t)(b * SPLIT + s) * DD + tid] = tot;
        if (tid == 0)
            ws[WS_P1SUM + b * SPLIT + s] =
                lds_sum[0] + lds_sum[1] + lds_sum[2] + lds_sum[3];
    } else {
        // ---- sentiment pass: two additive heads share the memory read.
        // Query/bias terms are softmax-shift-invariant -> omitted.
        const float4 wss4 = *(const float4*)(w_ss + lane * 4);
        const float4 wsa4 = *(const float4*)(w_sa + lane * 4);
        const float* base = smem_g + ((size_t)b * TT + t0) * DD + lane * 4;
        const float* mrow = mask + (size_t)b * TT + t0;
        float4 accss = make_float4(0.f, 0.f, 0.f, 0.f);
        float4 accsa = make_float4(0.f, 0.f, 0.f, 0.f);
        float lss = 0.f, lsa = 0.f;
        for (int r = 0; r < ROWS_PER_WAVE; r += 2) {
            float4 v0 = *(const float4*)(base + (size_t)r * DD);
            float4 v1 = *(const float4*)(base + (size_t)(r + 1) * DD);
            float m0 = mrow[r], m1 = mrow[r + 1];
            float dss0 = wave_reduce_add(dot4(v0, wss4));
            float dss1 = wave_reduce_add(dot4(v1, wss4));
            float dsa0 = wave_reduce_add(dot4(v0, wsa4));
            float dsa1 = wave_reduce_add(dot4(v1, wsa4));
            float ess0 = __expf(dss0) * m0, ess1 = __expf(dss1) * m1;
            float esa0 = __expf(dsa0) * m0, esa1 = __expf(dsa1) * m1;
            lss += ess0 + ess1;
            lsa += esa0 + esa1;
            accss.x += ess0 * v0.x + ess1 * v1.x;
            accss.y += ess0 * v0.y + ess1 * v1.y;
            accss.z += ess0 * v0.z + ess1 * v1.z;
            accss.w += ess0 * v0.w + ess1 * v1.w;
            accsa.x += esa0 * v0.x + esa1 * v1.x;
            accsa.y += esa0 * v0.y + esa1 * v1.y;
            accsa.z += esa0 * v0.z + esa1 * v1.z;
            accsa.w += esa0 * v0.w + esa1 * v1.w;
        }
        ((float4*)(lds_acc + wave * DD))[lane] = accss;
        ((float4*)(lds_acc + (WAVES + wave) * DD))[lane] = accsa;
        if (lane == 0) {
            lds_sum[wave] = lss;
            lds_sum[WAVES + wave] = lsa;
        }
        __syncthreads();
        float tot_ss = lds_acc[0 * DD + tid] + lds_acc[1 * DD + tid] +
                       lds_acc[2 * DD + tid] + lds_acc[3 * DD + tid];
        float tot_sa = lds_acc[(WAVES + 0) * DD + tid] + lds_acc[(WAVES + 1) * DD + tid] +
                       lds_acc[(WAVES + 2) * DD + tid] + lds_acc[(WAVES + 3) * DD + tid];
        ws[WS_P2ACC_SS + (size_t)(b * SPLIT + s) * DD + tid] = tot_ss;
        ws[WS_P2ACC_SA + (size_t)(b * SPLIT + s) * DD + tid] = tot_sa;
        if (tid == 0) {
            ws[WS_P2SUM_SS + b * SPLIT + s] =
                lds_sum[0] + lds_sum[1] + lds_sum[2] + lds_sum[3];
            ws[WS_P2SUM_SA + b * SPLIT + s] =
                lds_sum[4] + lds_sum[5] + lds_sum[6] + lds_sum[7];
        }
    }
}

// K_combine: grid (B, 2).  y=0: aspect_out = aspect + new_aspect.
// y=1: sentiment_out = 0.5*acc_ss/l_ss + 0.5*acc_sa/l_sa.
__global__ __launch_bounds__(DD) void combine_kernel(
    const float* __restrict__ aspect, const float* __restrict__ ws,
    float* __restrict__ out)
{
    const int b = blockIdx.x;
    const int d = threadIdx.x;
    if (blockIdx.y == 0) {
        float acc = 0.f, l = 0.f;
        #pragma unroll
        for (int s = 0; s < SPLIT; ++s)
            acc += ws[WS_P1ACC + (size_t)(b * SPLIT + s) * DD + d];
        #pragma unroll
        for (int s = 0; s < SPLIT; ++s)
            l += ws[WS_P1SUM + b * SPLIT + s];
        out[BB * DD + b * DD + d] = aspect[b * DD + d] + acc / l;
    } else {
        float ass = 0.f, asa = 0.f, lss = 0.f, lsa = 0.f;
        #pragma unroll
        for (int s = 0; s < SPLIT; ++s) {
            ass += ws[WS_P2ACC_SS + (size_t)(b * SPLIT + s) * DD + d];
            asa += ws[WS_P2ACC_SA + (size_t)(b * SPLIT + s) * DD + d];
        }
        #pragma unroll
        for (int s = 0; s < SPLIT; ++s) {
            lss += ws[WS_P2SUM_SS + b * SPLIT + s];
            lsa += ws[WS_P2SUM_SA + b * SPLIT + s];
        }
        out[b * DD + d] = 0.5f * (ass / lss) + 0.5f * (asa / lsa);
    }
}

extern "C" void kernel_launch(void* const* d_in, const int* in_sizes, int n_in,
                              void* d_out, int out_size, void* d_ws, size_t ws_size,
                              hipStream_t stream) {
    (void)in_sizes; (void)n_in; (void)out_size; (void)ws_size;
    // d_in order per setup_inputs():
    // 0 sentiment [B,D] (unused: query term is softmax-shift-invariant)
    // 1 aspect [B,D], 2 sentiment_memory [B,T,D], 3 aspect_memory [B,T,D],
    // 4 mask [B,T], 5 W_mul [D,D], 6 b_mul [1],
    // 7 w_ss [2D], 8 b_ss [1] (unused), 9 w_sa [2D], 10 b_sa [1] (unused)
    const float* aspect = (const float*)d_in[1];
    const float* smem   = (const float*)d_in[2];
    const float* amem   = (const float*)d_in[3];
    const float* mask   = (const float*)d_in[4];
    const float* W_mul  = (const float*)d_in[5];
    const float* b_mul  = (const float*)d_in[6];
    const float* w_ss   = (const float*)d_in[7];
    const float* w_sa   = (const float*)d_in[9];
    float* out = (float*)d_out;
    float* ws  = (float*)d_ws;

    mids_kernel<<<BB, DD, 0, stream>>>(aspect, W_mul, ws);
    pass_kernel<<<dim3(SPLIT, BB, 2), 256, 0, stream>>>(
        smem, amem, mask, w_ss, w_sa, b_mul, ws);
    combine_kernel<<<dim3(BB, 2), DD, 0, stream>>>(aspect, ws, out);
}